// Round 2
// baseline (333.264 us; speedup 1.0000x reference)
//
#include <hip/hip_runtime.h>

// Fused loss: 0.2 * mean(dx^2 - dy^2) + 0.8 * masked-MSE(target>0)
// dx = Sv(vert) ∘ D(horiz) on e = pred - target;  dy = D(vert) ∘ Sv(horiz)
//   Sv = [0.25, 1, 1.5, 1, 0.25], D = [-0.25, -0.5, 0, 0.5, 0.25]
// reflect-101 halo of 2 on e (exact).
//
// R8: barrier-free register-streaming stencil. R6/R7 post-mortem: the
// stage-everything -> __syncthreads -> compute structure is latency-bound
// (all waves drain vmcnt(0) before any compute; 2 blocks/CU leaves nothing
// to overlap). But the stencil is separable: vertical reuse lives in the
// rolling D/S register window, horizontal reuse is only +-2 cols == a
// lane-shift. So: NO LDS tiles, no staging barrier. Each wave streams a
// 256col x 32row band; per row: float4 load p/t, e=p-t, masked MSE,
// horizontal D/S via 4 x __shfl (lanes 0/63 patched from 2-float global
// halo loads), vertical combine from the rolling window. Full unroll lets
// the compiler hoist next-row loads over ~60 VALU ops of current-row work.

#define KROWS 32
#define NW 4      // waves per block

__device__ __forceinline__ int reflect101(int i, int n) {
    if (i < 0) i = -i;
    if (i >= n) i = 2 * n - 2 - i;
    return i;
}

__global__ __launch_bounds__(256, 2) void loss_main(
    const float* __restrict__ pred, const float* __restrict__ target,
    double* __restrict__ part, int H, int W)
{
    __shared__ float partials[NW][3];

    const int tid  = threadIdx.x;
    const int lane = tid & 63;
    const int w    = tid >> 6;
    const int c0   = blockIdx.x * 256;                 // strip start col
    const int r0   = (blockIdx.y * NW + w) * KROWS;    // band start row
    const int col  = c0 + lane * 4;

    // halo source columns (reflected only at image edges)
    const int clm2 = reflect101(c0 - 2, W);
    const int clm1 = reflect101(c0 - 1, W);
    const int crp0 = reflect101(c0 + 256, W);
    const int crp1 = reflect101(c0 + 257, W);
    const bool L0  = (lane == 0);
    const bool L63 = (lane == 63);

    float mse = 0.f, cnt = 0.f, g = 0.f;
    float4 D0, D1, D2, D3, D4, S0, S1, S2, S3, S4;

    // one input row: load, e, (mse), horizontal D/S with lane-shift halo
    auto dorow = [&](int ir, bool doMse, float4& D_, float4& S_) {
        const size_t base = (size_t)reflect101(ir, H) * W;
        const float4 p = *(const float4*)(pred   + base + col);
        const float4 t = *(const float4*)(target + base + col);
        // edge-lane halo loads issued early (predicated, 2 lanes only)
        float hp0 = 0.f, hp1 = 0.f, ht0 = 0.f, ht1 = 0.f;
        if (L0)  { hp0 = pred[base + clm2]; ht0 = target[base + clm2];
                   hp1 = pred[base + clm1]; ht1 = target[base + clm1]; }
        if (L63) { hp0 = pred[base + crp0]; ht0 = target[base + crp0];
                   hp1 = pred[base + crp1]; ht1 = target[base + crp1]; }
        float4 e;
        e.x = p.x - t.x; e.y = p.y - t.y; e.z = p.z - t.z; e.w = p.w - t.w;
        if (doMse) {
            if (t.x > 0.f) { mse += e.x * e.x; cnt += 1.f; }
            if (t.y > 0.f) { mse += e.y * e.y; cnt += 1.f; }
            if (t.z > 0.f) { mse += e.z * e.z; cnt += 1.f; }
            if (t.w > 0.f) { mse += e.w * e.w; cnt += 1.f; }
        }
        // neighbor columns: lane-1's e.z,e.w ; lane+1's e.x,e.y
        float lz = __shfl_up(e.z, 1);
        float lw = __shfl_up(e.w, 1);
        float rx = __shfl_down(e.x, 1);
        float ry = __shfl_down(e.y, 1);
        if (L0)  { lz = hp0 - ht0; lw = hp1 - ht1; }
        if (L63) { rx = hp0 - ht0; ry = hp1 - ht1; }
        // horizontal passes (same arithmetic as R6 hpass, a.z->lz a.w->lw
        // c.x->rx c.y->ry, b->e)
        D_.x = 0.25f * (e.z - lz) + 0.5f * (e.y - lw);
        D_.y = 0.25f * (e.w - lw) + 0.5f * (e.z - e.x);
        D_.z = 0.25f * (rx  - e.x) + 0.5f * (e.w - e.y);
        D_.w = 0.25f * (ry  - e.y) + 0.5f * (rx  - e.z);
        S_.x = 0.25f * (lz + e.z) + (lw  + e.y) + 1.5f * e.x;
        S_.y = 0.25f * (lw + e.w) + (e.x + e.z) + 1.5f * e.y;
        S_.z = 0.25f * (e.x + rx) + (e.y + e.w) + 1.5f * e.z;
        S_.w = 0.25f * (e.y + ry) + (e.z + rx ) + 1.5f * e.w;
    };

    // prologue: fill rows r0-2 .. r0+1
    dorow(r0 - 2, false, D0, S0);
    dorow(r0 - 1, false, D1, S1);
    dorow(r0,     true,  D2, S2);
    dorow(r0 + 1, true,  D3, S3);

#pragma unroll
    for (int k = 0; k < KROWS; ++k) {
        dorow(r0 + 2 + k, k < KROWS - 2, D4, S4);  // mse rows r0..r0+K-1 total
        // output row r0+k from window rows r0+k-2 .. r0+k+2
        const float dx0 = 0.25f * (D0.x + D4.x) + (D1.x + D3.x) + 1.5f * D2.x;
        const float dx1 = 0.25f * (D0.y + D4.y) + (D1.y + D3.y) + 1.5f * D2.y;
        const float dx2 = 0.25f * (D0.z + D4.z) + (D1.z + D3.z) + 1.5f * D2.z;
        const float dx3 = 0.25f * (D0.w + D4.w) + (D1.w + D3.w) + 1.5f * D2.w;
        const float dy0 = 0.25f * (S4.x - S0.x) + 0.5f * (S3.x - S1.x);
        const float dy1 = 0.25f * (S4.y - S0.y) + 0.5f * (S3.y - S1.y);
        const float dy2 = 0.25f * (S4.z - S0.z) + 0.5f * (S3.z - S1.z);
        const float dy3 = 0.25f * (S4.w - S0.w) + 0.5f * (S3.w - S1.w);
        g += (dx0 * dx0 - dy0 * dy0) + (dx1 * dx1 - dy1 * dy1)
           + (dx2 * dx2 - dy2 * dy2) + (dx3 * dx3 - dy3 * dy3);
        D0 = D1; D1 = D2; D2 = D3; D3 = D4;
        S0 = S1; S1 = S2; S2 = S3; S3 = S4;
    }

    // ---- reduction: wave shuffle -> LDS partials -> private ws slot ----
    for (int off = 32; off > 0; off >>= 1) {
        mse += __shfl_down(mse, off, 64);
        cnt += __shfl_down(cnt, off, 64);
        g   += __shfl_down(g,   off, 64);
    }
    if (lane == 0) {
        partials[w][0] = mse;
        partials[w][1] = cnt;
        partials[w][2] = g;
    }
    __syncthreads();
    if (tid == 0) {
        float m = 0.f, c2 = 0.f, gg = 0.f;
        for (int wv = 0; wv < NW; ++wv) {
            m  += partials[wv][0];
            c2 += partials[wv][1];
            gg += partials[wv][2];
        }
        const int bid = blockIdx.y * gridDim.x + blockIdx.x;
        double* slot = part + 3 * bid;
        slot[0] = (double)m;
        slot[1] = (double)c2;
        slot[2] = (double)gg;
    }
}

__global__ __launch_bounds__(256) void loss_final(
    const double* __restrict__ part, int nslots,
    float* __restrict__ out, double inv_hw)
{
    __shared__ double red[4][3];
    double m = 0.0, c = 0.0, g = 0.0;
    for (int s = threadIdx.x; s < nslots; s += 256) {
        m += part[3 * s];
        c += part[3 * s + 1];
        g += part[3 * s + 2];
    }
    for (int off = 32; off > 0; off >>= 1) {
        m += __shfl_down(m, off, 64);
        c += __shfl_down(c, off, 64);
        g += __shfl_down(g, off, 64);
    }
    const int w = threadIdx.x >> 6;
    if ((threadIdx.x & 63) == 0) { red[w][0] = m; red[w][1] = c; red[w][2] = g; }
    __syncthreads();
    if (threadIdx.x == 0) {
        m = red[0][0] + red[1][0] + red[2][0] + red[3][0];
        c = red[0][1] + red[1][1] + red[2][1] + red[3][1];
        g = red[0][2] + red[1][2] + red[2][2] + red[3][2];
        const double cnt = c < 1.0 ? 1.0 : c;
        out[0] = (float)(0.2 * (g * inv_hw) + 0.8 * (m / cnt));
    }
}

extern "C" void kernel_launch(void* const* d_in, const int* in_sizes, int n_in,
                              void* d_out, int out_size, void* d_ws, size_t ws_size,
                              hipStream_t stream) {
    const float* pred   = (const float*)d_in[0];
    const float* target = (const float*)d_in[1];
    float* out   = (float*)d_out;
    double* part = (double*)d_ws;

    const int H = 4096, W = 4096;
    dim3 grid(W / 256, H / (NW * KROWS));   // (16, 32) = 512 blocks
    const int nblocks = grid.x * grid.y;    // 512 slots = 12 KB of ws

    loss_main<<<grid, 256, 0, stream>>>(pred, target, part, H, W);
    loss_final<<<1, 256, 0, stream>>>(part, nblocks, out,
                                      1.0 / ((double)H * (double)W));
}

// Round 3
// 161.103 us; speedup vs baseline: 2.0686x; 2.0686x over previous
//
#include <hip/hip_runtime.h>

// Fused loss: 0.2 * mean(dx^2 - dy^2) + 0.8 * masked-MSE(target>0)
// dx = Sv(vert) ∘ D(horiz) on e = pred - target;  dy = D(vert) ∘ Sv(horiz)
//   Sv = [0.25, 1, 1.5, 1, 0.25], D = [-0.25, -0.5, 0, 0.5, 0.25]
// reflect-101 halo of 2 on e (exact; R6 tile math reused verbatim).
//
// R9: persistent double-buffered pipeline (T3/T4 pattern). R6's bottleneck
// was the stage -> __syncthreads (vmcnt(0) drain) -> compute lockstep with
// 2 blocks/CU. R8's register streaming spilled (WRITE_SIZE 169MB). Here:
// 1 block/CU, 512 threads (8 waves), LDS = 2 x (p,t) 36x264 tile = 152KB.
// Each block walks NT=8 y-tiles of its column strip. Per-wave vmem counts
// are exactly uniform (1 halo load + 9 global_load_lds per tile), so
// counted waits work: steady state waits vmcnt(10) (next tile's 10 ops
// stay in flight across the raw s_barrier) -- never vmcnt(0) in the loop.
// Compute of tile i overlaps the DMA of tile i+1.

#define TW 256
#define TH 32
#define LROWS 36   // TH + 4
#define LW 264     // row stride (words): interior 4..259, halo 2,3,260,261
#define NT 8       // tiles per block

__device__ __forceinline__ int reflect101(int i, int n) {
    if (i < 0) i = -i;
    if (i >= n) i = 2 * n - 2 - i;
    return i;
}

__device__ __forceinline__ void async16(const float* g, float* l) {
    __builtin_amdgcn_global_load_lds(
        (const __attribute__((address_space(1))) void*)g,
        (__attribute__((address_space(3))) void*)l, 16, 0, 0);
}

#define SFENCE()  __builtin_amdgcn_sched_barrier(0)
#define BAR()     asm volatile("s_barrier" ::: "memory")
#define VMCNT10() asm volatile("s_waitcnt vmcnt(10)" ::: "memory")
#define VMCNT0()  asm volatile("s_waitcnt vmcnt(0)" ::: "memory")
#define LGKM0()   asm volatile("s_waitcnt lgkmcnt(0)" ::: "memory")

__global__ __launch_bounds__(512, 1) void loss_main(
    const float* __restrict__ pred, const float* __restrict__ target,
    double* __restrict__ part, int H, int W)
{
    __shared__ float bufP[2][LROWS][LW];
    __shared__ float bufT[2][LROWS][LW];
    __shared__ float partials[8][3];

    const int tid  = threadIdx.x;
    const int lane = tid & 63;
    const int w    = tid >> 6;
    const int c0   = blockIdx.x * TW;
    const int ty0  = blockIdx.y * NT;

    // fixed per-thread halo geometry: 288 halo values (36 rows x 4 cols x 2
    // tensors); threads >= 288 duplicate (same addr, same value ds_write).
    int hvld = tid; if (hvld >= 288) hvld -= 288;
    const int htsel = (hvld >= 144);
    const int hrr   = hvld - (htsel ? 144 : 0);
    const int hrow  = hrr >> 2;
    const int hc    = hrr & 3;
    const int hlc   = (hc < 2) ? (2 + hc) : (258 + hc);
    const int hgc   = reflect101((hc < 2) ? (c0 - 2 + hc) : (c0 + 254 + hc), W);
    const float* hsrc = htsel ? target : pred;

    float mse = 0.f, cnt = 0.f, g = 0.f;

    // issue staging for tile ty into buffer bi: 1 halo load (volatile, kept
    // ahead of the DMAs so its auto-wait is vmcnt(9)) + 9 DMA per wave.
    auto stage = [&](int ty, int bi) -> float {
        const int r0 = ty * TH;
        const float hv = *(volatile const float*)(hsrc +
                         (size_t)reflect101(r0 - 2 + hrow, H) * W + hgc);
        SFENCE();
#pragma unroll
        for (int j = 0; j < 9; ++j) {
            const int idx = j * 8 + w;              // wave-uniform
            const int row = (idx < 36) ? idx : idx - 36;
            const int gr  = reflect101(r0 - 2 + row, H);
            const size_t goff = (size_t)gr * W + c0 + lane * 4;
            if (idx < 36) async16(pred   + goff, &bufP[bi][row][4]);
            else          async16(target + goff, &bufT[bi][row][4]);
        }
        SFENCE();
        return hv;
    };

    auto write_halo = [&](int bi, float hv) {
        float* base = htsel ? &bufT[bi][0][0] : &bufP[bi][0][0];
        base[hrow * LW + hlc] = hv;   // compiler auto-waits counted vmcnt
    };

    auto compute = [&](int bi) {
        const int cg = lane;
        const int rb = w * 4;          // window rows rb..rb+7, out rb+2..rb+5
        float4 D0, D1, D2, D3, D4, S0, S1, S2, S3, S4;

        auto hpass = [&](int rw, bool doMse, float4& D_, float4& S_) {
            const float4 p0 = *(const float4*)&bufP[bi][rw][4 * cg];
            const float4 p1 = *(const float4*)&bufP[bi][rw][4 * cg + 4];
            const float4 p2 = *(const float4*)&bufP[bi][rw][4 * cg + 8];
            const float4 t0 = *(const float4*)&bufT[bi][rw][4 * cg];
            const float4 t1 = *(const float4*)&bufT[bi][rw][4 * cg + 4];
            const float4 t2 = *(const float4*)&bufT[bi][rw][4 * cg + 8];
            const float e0z = p0.z - t0.z, e0w = p0.w - t0.w;
            const float e1x = p1.x - t1.x, e1y = p1.y - t1.y;
            const float e1z = p1.z - t1.z, e1w = p1.w - t1.w;
            const float e2x = p2.x - t2.x, e2y = p2.y - t2.y;
            D_.x = 0.25f * (e1z - e0z) + 0.5f * (e1y - e0w);
            D_.y = 0.25f * (e1w - e0w) + 0.5f * (e1z - e1x);
            D_.z = 0.25f * (e2x - e1x) + 0.5f * (e1w - e1y);
            D_.w = 0.25f * (e2y - e1y) + 0.5f * (e2x - e1z);
            S_.x = 0.25f * (e0z + e1z) + (e0w + e1y) + 1.5f * e1x;
            S_.y = 0.25f * (e0w + e1w) + (e1x + e1z) + 1.5f * e1y;
            S_.z = 0.25f * (e1x + e2x) + (e1y + e1w) + 1.5f * e1z;
            S_.w = 0.25f * (e1y + e2y) + (e1z + e2x) + 1.5f * e1w;
            if (doMse) {
                if (t1.x > 0.f) { mse += e1x * e1x; cnt += 1.f; }
                if (t1.y > 0.f) { mse += e1y * e1y; cnt += 1.f; }
                if (t1.z > 0.f) { mse += e1z * e1z; cnt += 1.f; }
                if (t1.w > 0.f) { mse += e1w * e1w; cnt += 1.f; }
            }
        };

        hpass(rb + 0, false, D0, S0);
        hpass(rb + 1, false, D1, S1);
        hpass(rb + 2, true,  D2, S2);
        hpass(rb + 3, true,  D3, S3);

#pragma unroll
        for (int k = 0; k < 4; ++k) {
            hpass(rb + 4 + k, (k < 2), D4, S4);
            const float dx0 = 0.25f * (D0.x + D4.x) + (D1.x + D3.x) + 1.5f * D2.x;
            const float dx1 = 0.25f * (D0.y + D4.y) + (D1.y + D3.y) + 1.5f * D2.y;
            const float dx2 = 0.25f * (D0.z + D4.z) + (D1.z + D3.z) + 1.5f * D2.z;
            const float dx3 = 0.25f * (D0.w + D4.w) + (D1.w + D3.w) + 1.5f * D2.w;
            const float dy0 = 0.25f * (S4.x - S0.x) + 0.5f * (S3.x - S1.x);
            const float dy1 = 0.25f * (S4.y - S0.y) + 0.5f * (S3.y - S1.y);
            const float dy2 = 0.25f * (S4.z - S0.z) + 0.5f * (S3.z - S1.z);
            const float dy3 = 0.25f * (S4.w - S0.w) + 0.5f * (S3.w - S1.w);
            g += (dx0 * dx0 - dy0 * dy0) + (dx1 * dx1 - dy1 * dy1)
               + (dx2 * dx2 - dy2 * dy2) + (dx3 * dx3 - dy3 * dy3);
            D0 = D1; D1 = D2; D2 = D3; D3 = D4;
            S0 = S1; S1 = S2; S2 = S3; S3 = S4;
        }
    };

    // ---- prologue: fill both buffers, pipeline depth 1 ----
    float hv0 = stage(ty0 + 0, 0);
    float hv1 = stage(ty0 + 1, 1);
    write_halo(0, hv0);                 // auto vmcnt(19): halo0 ready
    VMCNT10(); LGKM0(); BAR(); SFENCE();   // DMA(0) done; DMA(1) in flight

    // ---- main loop: compute(i) overlaps DMA(i+1); never vmcnt(0) until tail
#pragma unroll
    for (int i = 0; i < NT; ++i) {
        const int cur = i & 1;
        if (i + 1 < NT)
            write_halo(cur ^ 1, (cur ^ 1) ? hv1 : hv0);  // auto vmcnt(9)
        compute(cur);
        if (i + 2 < NT) {
            BAR(); SFENCE();            // all waves done reading buf[cur]
            if (cur) hv1 = stage(ty0 + i + 2, cur);
            else     hv0 = stage(ty0 + i + 2, cur);
            VMCNT10(); LGKM0(); BAR(); SFENCE();  // buf[cur^1] ready; 10 in flight
        } else if (i + 1 < NT) {
            VMCNT0(); LGKM0(); BAR(); SFENCE();   // tail: drain last DMA
        }
    }

    // ---- reduction: wave shuffle -> LDS partials -> private ws slot ----
    for (int off = 32; off > 0; off >>= 1) {
        mse += __shfl_down(mse, off, 64);
        cnt += __shfl_down(cnt, off, 64);
        g   += __shfl_down(g,   off, 64);
    }
    if (lane == 0) {
        partials[w][0] = mse;
        partials[w][1] = cnt;
        partials[w][2] = g;
    }
    __syncthreads();
    if (tid == 0) {
        float m = 0.f, c2 = 0.f, gg = 0.f;
        for (int wv = 0; wv < 8; ++wv) {
            m  += partials[wv][0];
            c2 += partials[wv][1];
            gg += partials[wv][2];
        }
        const int bid = blockIdx.y * gridDim.x + blockIdx.x;
        double* slot = part + 3 * bid;
        slot[0] = (double)m;
        slot[1] = (double)c2;
        slot[2] = (double)gg;
    }
}

__global__ __launch_bounds__(256) void loss_final(
    const double* __restrict__ part, int nslots,
    float* __restrict__ out, double inv_hw)
{
    __shared__ double red[4][3];
    double m = 0.0, c = 0.0, g = 0.0;
    for (int s = threadIdx.x; s < nslots; s += 256) {
        m += part[3 * s];
        c += part[3 * s + 1];
        g += part[3 * s + 2];
    }
    for (int off = 32; off > 0; off >>= 1) {
        m += __shfl_down(m, off, 64);
        c += __shfl_down(c, off, 64);
        g += __shfl_down(g, off, 64);
    }
    const int w = threadIdx.x >> 6;
    if ((threadIdx.x & 63) == 0) { red[w][0] = m; red[w][1] = c; red[w][2] = g; }
    __syncthreads();
    if (threadIdx.x == 0) {
        m = red[0][0] + red[1][0] + red[2][0] + red[3][0];
        c = red[0][1] + red[1][1] + red[2][1] + red[3][1];
        g = red[0][2] + red[1][2] + red[2][2] + red[3][2];
        const double cnt = c < 1.0 ? 1.0 : c;
        out[0] = (float)(0.2 * (g * inv_hw) + 0.8 * (m / cnt));
    }
}

extern "C" void kernel_launch(void* const* d_in, const int* in_sizes, int n_in,
                              void* d_out, int out_size, void* d_ws, size_t ws_size,
                              hipStream_t stream) {
    const float* pred   = (const float*)d_in[0];
    const float* target = (const float*)d_in[1];
    float* out   = (float*)d_out;
    double* part = (double*)d_ws;

    const int H = 4096, W = 4096;
    dim3 grid(W / TW, H / (TH * NT));   // (16, 16) = 256 blocks = 1/CU
    const int nblocks = grid.x * grid.y;   // 256 slots = 6 KB of ws

    loss_main<<<grid, 512, 0, stream>>>(pred, target, part, H, W);
    loss_final<<<1, 256, 0, stream>>>(part, nblocks, out,
                                      1.0 / ((double)H * (double)W));
}

// Round 4
// 154.671 us; speedup vs baseline: 2.1547x; 1.0416x over previous
//
#include <hip/hip_runtime.h>

// Fused loss: 0.2 * mean(dx^2 - dy^2) + 0.8 * masked-MSE(target>0)
// dx = Sv(vert) ∘ D(horiz) on e = pred - target;  dy = D(vert) ∘ Sv(horiz)
//   Sv = [0.25, 1, 1.5, 1, 0.25], D = [-0.25, -0.5, 0, 0.5, 0.25]
// reflect-101 halo of 2 (exact; D/S/emit formulas verbatim from R8, which
// passed absmax 0.0).
//
// R10: pure register streaming, NO LDS, no barriers. R6/R9 post-mortem:
// every LDS-staged variant (lockstep, counted-vmcnt pipeline) sits at
// 46-56us, VALUBusy ~31%, HBM ~20% -- staging once-consumed data through
// LDS serializes the CU. Here each wave streams a 256col x 16row band:
// per row, 3 aligned loads per tensor (float4 center + float2 left/right
// halo -- no shuffles, no unaligned access), rolling 5-row D/S register
// window, image-edge reflection via address clamp + 2 cndmask patches.
// MSE count via ballot/popc (scalar pipe). 14-iter hot loop, unroll 2
// (bounded body -- R8's full unroll spilled: WRITE_SIZE 169MB sentinel).
// 1024 blocks, all resident (4/CU at <=128 VGPR), 16 waves/CU.

#define NW 4        // waves per block
#define KR 16       // output rows per wave band

__device__ __forceinline__ int reflect101(int i, int n) {
    if (i < 0) i = -i;
    if (i >= n) i = 2 * n - 2 - i;
    return i;
}

__global__ __launch_bounds__(256, 4) void loss_main(
    const float* __restrict__ pred, const float* __restrict__ target,
    double* __restrict__ part, int H, int W)
{
    __shared__ float partials[NW][3];

    const int tid  = threadIdx.x;
    const int lane = tid & 63;
    const int w    = tid >> 6;
    const int c0   = blockIdx.x * 256;
    const int band = blockIdx.y * NW + w;
    const int r0   = band * KR;

    // per-lane column offsets (loop-invariant)
    const int cc = c0 + lane * 4;                        // center float4 col
    const int cl = (cc - 2 < 0) ? 0 : (cc - 2);          // left float2 (clamped)
    const int cr = (cc + 4 > W - 2) ? (W - 2) : (cc + 4);// right float2 (clamped)
    const bool patL = (cc == 0);           // lane0 of block0: lz := e.z
    const bool patR = (cc + 4 > W - 2);    // lane63 of last block: ry := e.y

    float mse = 0.f, g = 0.f;
    unsigned cntU = 0;

    float4 D0, D1, D2, D3, D4, S0, S1, S2, S3, S4;

    auto dorow = [&](int ir, bool doMse, float4& D_, float4& S_) {
        const size_t rb = (size_t)reflect101(ir, H) * W;
        const float4 pc = *(const float4*)(pred   + rb + cc);
        const float2 pl = *(const float2*)(pred   + rb + cl);
        const float2 pr = *(const float2*)(pred   + rb + cr);
        const float4 tc = *(const float4*)(target + rb + cc);
        const float2 tl = *(const float2*)(target + rb + cl);
        const float2 tr = *(const float2*)(target + rb + cr);
        float4 e;
        e.x = pc.x - tc.x; e.y = pc.y - tc.y;
        e.z = pc.z - tc.z; e.w = pc.w - tc.w;
        float lz = pl.x - tl.x;          // e(c-2)
        float lw = pl.y - tl.y;          // e(c-1)
        float rx = pr.x - tr.x;          // e(c+4)
        float ry = pr.y - tr.y;          // e(c+5)
        // image-edge reflect patches (clamped loads give e0,e1 / e(W-2),e(W-1)):
        // reflect(-2)=2 -> e.z ; lw already e(1). reflect(W+1)=W-3 -> e.y ;
        // rx already e(W-2).
        lz = patL ? e.z : lz;
        ry = patR ? e.y : ry;
        if (doMse) {
            cntU += __popcll(__ballot(tc.x > 0.f)) + __popcll(__ballot(tc.y > 0.f))
                  + __popcll(__ballot(tc.z > 0.f)) + __popcll(__ballot(tc.w > 0.f));
            mse = fmaf(tc.x > 0.f ? e.x : 0.f, e.x, mse);
            mse = fmaf(tc.y > 0.f ? e.y : 0.f, e.y, mse);
            mse = fmaf(tc.z > 0.f ? e.z : 0.f, e.z, mse);
            mse = fmaf(tc.w > 0.f ? e.w : 0.f, e.w, mse);
        }
        D_.x = 0.25f * (e.z - lz) + 0.5f * (e.y - lw);
        D_.y = 0.25f * (e.w - lw) + 0.5f * (e.z - e.x);
        D_.z = 0.25f * (rx  - e.x) + 0.5f * (e.w - e.y);
        D_.w = 0.25f * (ry  - e.y) + 0.5f * (rx  - e.z);
        S_.x = 0.25f * (lz + e.z) + (lw  + e.y) + 1.5f * e.x;
        S_.y = 0.25f * (lw + e.w) + (e.x + e.z) + 1.5f * e.y;
        S_.z = 0.25f * (e.x + rx) + (e.y + e.w) + 1.5f * e.z;
        S_.w = 0.25f * (e.y + ry) + (e.z + rx ) + 1.5f * e.w;
    };

    auto emit = [&]() {
        const float dx0 = 0.25f * (D0.x + D4.x) + (D1.x + D3.x) + 1.5f * D2.x;
        const float dx1 = 0.25f * (D0.y + D4.y) + (D1.y + D3.y) + 1.5f * D2.y;
        const float dx2 = 0.25f * (D0.z + D4.z) + (D1.z + D3.z) + 1.5f * D2.z;
        const float dx3 = 0.25f * (D0.w + D4.w) + (D1.w + D3.w) + 1.5f * D2.w;
        const float dy0 = 0.25f * (S4.x - S0.x) + 0.5f * (S3.x - S1.x);
        const float dy1 = 0.25f * (S4.y - S0.y) + 0.5f * (S3.y - S1.y);
        const float dy2 = 0.25f * (S4.z - S0.z) + 0.5f * (S3.z - S1.z);
        const float dy3 = 0.25f * (S4.w - S0.w) + 0.5f * (S3.w - S1.w);
        g += (dx0 * dx0 - dy0 * dy0) + (dx1 * dx1 - dy1 * dy1)
           + (dx2 * dx2 - dy2 * dy2) + (dx3 * dx3 - dy3 * dy3);
    };
    auto shift = [&]() {
        D0 = D1; D1 = D2; D2 = D3; D3 = D4;
        S0 = S1; S1 = S2; S2 = S3; S3 = S4;
    };

    // prologue: rows r0-2 .. r0+1. MSE exactly on rows r0, r0+1 (for band 0
    // the reflected dup rows 2,1 carry doMse=false -> each row counted once).
    dorow(r0 - 2, false, D0, S0);
    dorow(r0 - 1, false, D1, S1);
    dorow(r0 + 0, true,  D2, S2);
    dorow(r0 + 1, true,  D3, S3);

    // hot loop: rows r0+2 .. r0+15, all with MSE, zero runtime predicates
#pragma unroll 2
    for (int k = 0; k < KR - 2; ++k) {
        dorow(r0 + 2 + k, true, D4, S4);
        emit();
        shift();
    }
    // tail: rows r0+16, r0+17 (next band's MSE rows / reflected) -> no MSE
    dorow(r0 + KR,     false, D4, S4); emit(); shift();
    dorow(r0 + KR + 1, false, D4, S4); emit();

    // ---- reduction: wave shuffle -> LDS partials -> private ws slot ----
    for (int off = 32; off > 0; off >>= 1) {
        mse += __shfl_down(mse, off, 64);
        g   += __shfl_down(g,   off, 64);
    }
    if (lane == 0) {
        partials[w][0] = mse;
        partials[w][1] = (float)cntU;   // ballot count: wave-uniform
        partials[w][2] = g;
    }
    __syncthreads();
    if (tid == 0) {
        float m = 0.f, c2 = 0.f, gg = 0.f;
        for (int wv = 0; wv < NW; ++wv) {
            m  += partials[wv][0];
            c2 += partials[wv][1];
            gg += partials[wv][2];
        }
        const int bid = blockIdx.y * gridDim.x + blockIdx.x;
        double* slot = part + 3 * bid;
        slot[0] = (double)m;
        slot[1] = (double)c2;
        slot[2] = (double)gg;
    }
}

__global__ __launch_bounds__(256) void loss_final(
    const double* __restrict__ part, int nslots,
    float* __restrict__ out, double inv_hw)
{
    __shared__ double red[4][3];
    double m = 0.0, c = 0.0, g = 0.0;
    for (int s = threadIdx.x; s < nslots; s += 256) {
        m += part[3 * s];
        c += part[3 * s + 1];
        g += part[3 * s + 2];
    }
    for (int off = 32; off > 0; off >>= 1) {
        m += __shfl_down(m, off, 64);
        c += __shfl_down(c, off, 64);
        g += __shfl_down(g, off, 64);
    }
    const int w = threadIdx.x >> 6;
    if ((threadIdx.x & 63) == 0) { red[w][0] = m; red[w][1] = c; red[w][2] = g; }
    __syncthreads();
    if (threadIdx.x == 0) {
        m = red[0][0] + red[1][0] + red[2][0] + red[3][0];
        c = red[0][1] + red[1][1] + red[2][1] + red[3][1];
        g = red[0][2] + red[1][2] + red[2][2] + red[3][2];
        const double cnt = c < 1.0 ? 1.0 : c;
        out[0] = (float)(0.2 * (g * inv_hw) + 0.8 * (m / cnt));
    }
}

extern "C" void kernel_launch(void* const* d_in, const int* in_sizes, int n_in,
                              void* d_out, int out_size, void* d_ws, size_t ws_size,
                              hipStream_t stream) {
    const float* pred   = (const float*)d_in[0];
    const float* target = (const float*)d_in[1];
    float* out   = (float*)d_out;
    double* part = (double*)d_ws;

    const int H = 4096, W = 4096;
    dim3 grid(W / 256, H / (NW * KR));    // (16, 64) = 1024 blocks, all resident
    const int nblocks = grid.x * grid.y;  // 1024 slots = 24 KB of ws

    loss_main<<<grid, 256, 0, stream>>>(pred, target, part, H, W);
    loss_final<<<1, 256, 0, stream>>>(part, nblocks, out,
                                      1.0 / ((double)H * (double)W));
}